// Round 6
// baseline (519.566 us; speedup 1.0000x reference)
//
#include <hip/hip_runtime.h>
#include <hip/hip_fp16.h>

// GCN 2-layer: out = D_in^-1/2 A D_out^-1/2 (relu(D_in^-1/2 A D_out^-1/2 X W1 + b1)) W2 + b2
// Strategy: project-then-aggregate (matmul commutes with segment_sum),
// CSR-by-dst built per call. R5: ZERO device-scope atomics anywhere.
// R1: 3-phase parallel scan. R2: register-tiled GEMM. R3: rank-based CSR fill.
// R4: LDS-binned histograms + fp16 Y (atomic pipe ~24 G ops/s was the bound).
// R5: CSR build fully via binned LDS scatter: per-slice dst histograms ->
//     column-prefix base offsets -> (slice,bin) blocks assign unique slots
//     with LDS atomicAdd on base-preloaded counters. rank/fill_csr deleted.

static inline size_t align256(size_t x) { return (x + 255) & ~(size_t)255; }

#define HIST_BIN 8192
#define HIST_SLICES 32

// Per-slice binned histogram (LDS atomics only). partial[s][v] = count of
// `keys` in slice s equal to v.
__global__ __launch_bounds__(256)
void hist_partial_kernel(const int* __restrict__ keys,
                         int* __restrict__ partial,   // [HIST_SLICES][N]
                         int N, int E, int slice_len) {
    __shared__ int h[HIST_BIN];
    const int s = blockIdx.x;             // edge slice
    const int lo = blockIdx.y * HIST_BIN; // node-bin base
    for (int i = threadIdx.x; i < HIST_BIN; i += 256) h[i] = 0;
    __syncthreads();
    const int beg = s * slice_len;
    const int end = min(beg + slice_len, E);
    for (int i = beg + threadIdx.x; i < end; i += 256) {
        int v = keys[i] - lo;
        if ((unsigned)v < (unsigned)HIST_BIN) atomicAdd(&h[v], 1);  // LDS atomic
    }
    __syncthreads();
    const int hi = min(lo + HIST_BIN, N);
    int* p = partial + (size_t)s * N;
    for (int v = lo + threadIdx.x; v < hi; v += 256) p[v] = h[v - lo];
}

__global__ void hist_reduce_kernel(const int* __restrict__ partial,
                                   int* __restrict__ cnt, int N) {
    const int v = blockIdx.x * 256 + threadIdx.x;
    if (v >= N) return;
    int sum = 0;
#pragma unroll 4
    for (int s = 0; s < HIST_SLICES; ++s) sum += partial[(size_t)s * N + v];
    cnt[v] = sum;
}

// ---- 3-phase parallel exclusive scan of cnt_in -> row_ptr ----
__global__ __launch_bounds__(512)
void scan_local_kernel(const int* __restrict__ cnt_in,
                       int* __restrict__ row_ptr,
                       int* __restrict__ block_sums, int N) {
    __shared__ int tmp[512];
    const int t = threadIdx.x;
    const int gid = blockIdx.x * 512 + t;
    int v = (gid < N) ? cnt_in[gid] : 0;
    tmp[t] = v;
    __syncthreads();
    for (int off = 1; off < 512; off <<= 1) {
        int u = (t >= off) ? tmp[t - off] : 0;
        __syncthreads();
        tmp[t] += u;
        __syncthreads();
    }
    if (gid < N) row_ptr[gid] = tmp[t] - v;      // exclusive
    if (t == 511) block_sums[blockIdx.x] = tmp[511];
}

__global__ __launch_bounds__(1024)
void scan_sums_kernel(int* __restrict__ block_sums, int nb) {
    __shared__ int tmp[1024];
    const int t = threadIdx.x;
    int v = (t < nb) ? block_sums[t] : 0;
    tmp[t] = v;
    __syncthreads();
    for (int off = 1; off < 1024; off <<= 1) {
        int u = (t >= off) ? tmp[t - off] : 0;
        __syncthreads();
        tmp[t] += u;
        __syncthreads();
    }
    if (t < nb) block_sums[t] = tmp[t] - v;      // exclusive
}

__global__ __launch_bounds__(512)
void scan_add_kernel(int* __restrict__ row_ptr,
                     const int* __restrict__ block_sums, int N, int E) {
    const int gid = blockIdx.x * 512 + threadIdx.x;
    if (gid < N) row_ptr[gid] += block_sums[blockIdx.x];
    if (gid == 0) row_ptr[N] = E;
}

// In-place column scan: partial[s][v] <- row_ptr[v] + sum_{s'<s} partial[s'][v].
// Coalesced over v for each s.
__global__ void base_transform_kernel(int* __restrict__ partial,
                                      const int* __restrict__ row_ptr, int N) {
    const int v = blockIdx.x * 256 + threadIdx.x;
    if (v >= N) return;
    int run = row_ptr[v];
#pragma unroll 4
    for (int s = 0; s < HIST_SLICES; ++s) {
        size_t idx = (size_t)s * N + v;
        int t = partial[idx];
        partial[idx] = run;
        run += t;
    }
}

// Scatter edges into CSR: block (slice s, bin b) preloads base[s][bin] into
// LDS counters; each in-bin edge takes a unique slot via LDS atomicAdd.
__global__ __launch_bounds__(256)
void scatter_csr_kernel(const int* __restrict__ src,
                        const int* __restrict__ dst,
                        const int* __restrict__ base,   // [HIST_SLICES][N]
                        int* __restrict__ csr_src,
                        int N, int E, int slice_len) {
    __shared__ int h[HIST_BIN];
    const int s = blockIdx.x;
    const int lo = blockIdx.y * HIST_BIN;
    const int span = min(HIST_BIN, N - lo);
    const int* bs = base + (size_t)s * N + lo;
    for (int j = threadIdx.x; j < span; j += 256) h[j] = bs[j];
    __syncthreads();
    const int beg = s * slice_len;
    const int end = min(beg + slice_len, E);
    for (int i = beg + threadIdx.x; i < end; i += 256) {
        int v = dst[i] - lo;
        if ((unsigned)v < (unsigned)span) {
            int pos = atomicAdd(&h[v], 1);      // LDS atomic -> unique slot
            csr_src[pos] = src[i];
        }
    }
}

// Y[n][j] = (sum_k X[n][k] * W[k][j]) * rsqrt(max(cnt_out[n],1)), stored fp16.
// Block: 256 threads = 64 rows x 64 cols; thread computes 4 rows x 4 cols.
template <int K>
__global__ __launch_bounds__(256)
void gemm_scale_kernel(const float* __restrict__ X, const float* __restrict__ W,
                       const int* __restrict__ cnt_out,
                       __half* __restrict__ Y, int N) {
    __shared__ float Ws[K][64];
    const int t = threadIdx.x;
    for (int i = t; i < K * 64; i += 256) Ws[i >> 6][i & 63] = W[i];
    __syncthreads();

    const int cid = t & 15;            // cols 4*cid .. 4*cid+3
    const int rid = t >> 4;            // rows rowBase+4*rid .. +3
    const int rowBase = blockIdx.x * 64;

    const float* xp[4];
    int r[4];
#pragma unroll
    for (int i = 0; i < 4; ++i) {
        r[i] = rowBase + 4 * rid + i;
        xp[i] = X + (size_t)min(r[i], N - 1) * K;
    }

    float acc[4][4] = {};
#pragma unroll 2
    for (int kq = 0; kq < K / 4; ++kq) {
        const int k = kq * 4;
        float4 xv[4], wv[4];
#pragma unroll
        for (int i = 0; i < 4; ++i) xv[i] = *(const float4*)(xp[i] + k);
#pragma unroll
        for (int tt = 0; tt < 4; ++tt) wv[tt] = *(const float4*)&Ws[k + tt][4 * cid];
#pragma unroll
        for (int i = 0; i < 4; ++i) {
            const float* xf = (const float*)&xv[i];
#pragma unroll
            for (int tt = 0; tt < 4; ++tt) {
                const float a = xf[tt];
                const float* wf = (const float*)&wv[tt];
                acc[i][0] += a * wf[0];
                acc[i][1] += a * wf[1];
                acc[i][2] += a * wf[2];
                acc[i][3] += a * wf[3];
            }
        }
    }

#pragma unroll
    for (int i = 0; i < 4; ++i) {
        if (r[i] < N) {
            float sc = rsqrtf((float)max(cnt_out[r[i]], 1));
            __half2* yp = (__half2*)&Y[(size_t)r[i] * 64 + 4 * cid];
            yp[0] = __halves2half2(__float2half_rn(acc[i][0] * sc),
                                   __float2half_rn(acc[i][1] * sc));
            yp[1] = __halves2half2(__float2half_rn(acc[i][2] * sc),
                                   __float2half_rn(acc[i][3] * sc));
        }
    }
}

// out[n][f] = (sum_{in-edges} Y[src][f]) * rsqrt(max(cnt_in[n],1)) + bias[f]
// One wave per node (lane = feature), 4 nodes / 256-thread block. No atomics.
template <bool RELU>
__global__ __launch_bounds__(256)
void aggregate_kernel(const __half* __restrict__ Y,
                      const int* __restrict__ row_ptr,
                      const int* __restrict__ csr_src,
                      const int* __restrict__ cnt_in,
                      const float* __restrict__ bias,
                      float* __restrict__ out, int N) {
    const int f = threadIdx.x & 63;
    const int n = blockIdx.x * 4 + (threadIdx.x >> 6);
    if (n >= N) return;

    const int start = row_ptr[n];
    const int end   = row_ptr[n + 1];

    float acc = 0.f;
    int e = start;
    for (; e + 4 <= end; e += 4) {
        int s0 = csr_src[e];
        int s1 = csr_src[e + 1];
        int s2 = csr_src[e + 2];
        int s3 = csr_src[e + 3];
        float v0 = __half2float(Y[(size_t)s0 * 64 + f]);
        float v1 = __half2float(Y[(size_t)s1 * 64 + f]);
        float v2 = __half2float(Y[(size_t)s2 * 64 + f]);
        float v3 = __half2float(Y[(size_t)s3 * 64 + f]);
        acc += v0 + v1 + v2 + v3;
    }
    for (; e < end; ++e) acc += __half2float(Y[(size_t)csr_src[e] * 64 + f]);

    float sc = rsqrtf((float)max(cnt_in[n], 1));
    float r = acc * sc + bias[f];
    if (RELU) r = fmaxf(r, 0.f);
    out[(size_t)n * 64 + f] = r;
}

extern "C" void kernel_launch(void* const* d_in, const int* in_sizes, int n_in,
                              void* d_out, int out_size, void* d_ws, size_t ws_size,
                              hipStream_t stream) {
    const float* x   = (const float*)d_in[0];
    const int*   src = (const int*)d_in[1];
    const int*   dst = (const int*)d_in[2];
    const float* W1  = (const float*)d_in[3];
    const float* b1  = (const float*)d_in[4];
    const float* W2  = (const float*)d_in[5];
    const float* b2  = (const float*)d_in[6];
    float* out = (float*)d_out;

    const int N = in_sizes[0] / 128;   // 100000
    const int E = in_sizes[1];         // 1600000

    const int SCAN_B = 512;
    const int nb = (N + SCAN_B - 1) / SCAN_B;   // 196 blocks

    // Workspace (~33 MB), time-shared:
    //   partial_src [32][N] ints (12.8 MB) -> later Y fp16 (12.8 MB)
    //   partial_dst [32][N] ints (12.8 MB) -> becomes base, dead after scatter
    // d_out doubles as the hidden-layer (H) buffer.
    char* ws = (char*)d_ws;
    size_t off = 0;
    int* partial_src = (int*)(ws + off); off = align256(off + (size_t)HIST_SLICES * N * sizeof(int));
    int* partial_dst = (int*)(ws + off); off = align256(off + (size_t)HIST_SLICES * N * sizeof(int));
    int* csr_src     = (int*)(ws + off); off = align256(off + (size_t)E * sizeof(int));
    int* cnt_out     = (int*)(ws + off); off = align256(off + (size_t)N * sizeof(int));
    int* cnt_in      = (int*)(ws + off); off = align256(off + (size_t)N * sizeof(int));
    int* row_ptr     = (int*)(ws + off); off = align256(off + (size_t)(N + 1) * sizeof(int));
    int* blk_sums    = (int*)(ws + off); off = align256(off + (size_t)nb * sizeof(int));

    __half* Y = (__half*)partial_src;     // fp16 projected features (time-shared)

    const int slice_len = (E + HIST_SLICES - 1) / HIST_SLICES;
    const int nbins = (N + HIST_BIN - 1) / HIST_BIN;
    const dim3 hgrid(HIST_SLICES, nbins);

    // Degree histograms (LDS atomics only)
    hist_partial_kernel<<<hgrid, 256, 0, stream>>>(src, partial_src, N, E, slice_len);
    hist_partial_kernel<<<hgrid, 256, 0, stream>>>(dst, partial_dst, N, E, slice_len);
    hist_reduce_kernel<<<(N + 255) / 256, 256, 0, stream>>>(partial_src, cnt_out, N);
    hist_reduce_kernel<<<(N + 255) / 256, 256, 0, stream>>>(partial_dst, cnt_in, N);

    // row_ptr scan, base offsets, atomic-free scatter
    scan_local_kernel<<<nb, SCAN_B, 0, stream>>>(cnt_in, row_ptr, blk_sums, N);
    scan_sums_kernel<<<1, 1024, 0, stream>>>(blk_sums, nb);
    scan_add_kernel<<<nb, SCAN_B, 0, stream>>>(row_ptr, blk_sums, N, E);
    base_transform_kernel<<<(N + 255) / 256, 256, 0, stream>>>(partial_dst, row_ptr, N);
    scatter_csr_kernel<<<hgrid, 256, 0, stream>>>(src, dst, partial_dst, csr_src, N, E, slice_len);

    const int gemm_blocks = (N + 63) / 64;   // 64 rows per block
    const int agg_blocks  = (N + 3) / 4;     // 4 nodes per block

    // Layer 1: Y = fp16[(X @ W1) * rs_out] ; agg -> d_out (hidden, relu)
    gemm_scale_kernel<128><<<gemm_blocks, 256, 0, stream>>>(x, W1, cnt_out, Y, N);
    aggregate_kernel<true><<<agg_blocks, 256, 0, stream>>>(Y, row_ptr, csr_src, cnt_in, b1, out, N);

    // Layer 2: Y = fp16[(H @ W2) * rs_out] ; agg -> d_out (final)
    gemm_scale_kernel<64><<<gemm_blocks, 256, 0, stream>>>(out, W2, cnt_out, Y, N);
    aggregate_kernel<false><<<agg_blocks, 256, 0, stream>>>(Y, row_ptr, csr_src, cnt_in, b2, out, N);
}

// Round 7
// 417.846 us; speedup vs baseline: 1.2434x; 1.2434x over previous
//
#include <hip/hip_runtime.h>
#include <hip/hip_fp16.h>

// GCN 2-layer: out = D_in^-1/2 A D_out^-1/2 (relu(D_in^-1/2 A D_out^-1/2 X W1 + b1)) W2 + b2
// Strategy: project-then-aggregate (matmul commutes with segment_sum),
// CSR-by-dst built per call.
// R1: parallel scan. R2: register-tiled GEMM. R3: rank-based CSR fill.
// R4: LDS-binned histogram for cnt_out + fp16 Y (device atomic pipe ~24 G/s).
// R5 FAILED: binned LDS scatter = 95 us (16% occupancy, 13x redundant reads).
// R6: revert to atomic ranks (67 us is the atomic-pipe floor for 1.6M ranks);
//     pack (rank<<17|dst) to drop a fill stream; half2 2-edge-per-wave
//     aggregate (half the VMEM issue, 2x MLP).

static inline size_t align256(size_t x) { return (x + 255) & ~(size_t)255; }

#define HIST_BIN 8192
#define HIST_SLICES 64

// Per-slice binned histogram of src (LDS atomics only) -> out-degrees.
__global__ __launch_bounds__(256)
void hist_partial_kernel(const int* __restrict__ keys,
                         int* __restrict__ partial,   // [HIST_SLICES][N]
                         int N, int E, int slice_len) {
    __shared__ int h[HIST_BIN];
    const int s = blockIdx.x;             // edge slice
    const int lo = blockIdx.y * HIST_BIN; // node-bin base
    for (int i = threadIdx.x; i < HIST_BIN; i += 256) h[i] = 0;
    __syncthreads();
    const int beg = s * slice_len;
    const int end = min(beg + slice_len, E);
    for (int i = beg + threadIdx.x; i < end; i += 256) {
        int v = keys[i] - lo;
        if ((unsigned)v < (unsigned)HIST_BIN) atomicAdd(&h[v], 1);  // LDS atomic
    }
    __syncthreads();
    const int hi = min(lo + HIST_BIN, N);
    int* p = partial + (size_t)s * N;
    for (int v = lo + threadIdx.x; v < hi; v += 256) p[v] = h[v - lo];
}

__global__ void hist_reduce_kernel(const int* __restrict__ partial,
                                   int* __restrict__ cnt, int N) {
    const int v = blockIdx.x * 256 + threadIdx.x;
    if (v >= N) return;
    int sum = 0;
#pragma unroll 4
    for (int s = 0; s < HIST_SLICES; ++s) sum += partial[(size_t)s * N + v];
    cnt[v] = sum;
}

// In-degree ranks via device atomics (the irreducible 1.6M-atomic pass).
// Packs rank<<17 | dst so fill_csr needs one fewer stream.
__global__ void rank_kernel(const int* __restrict__ dst,
                            int* __restrict__ cnt_in,
                            unsigned* __restrict__ packed, int E) {
    int stride = gridDim.x * blockDim.x;
    for (int i = blockIdx.x * blockDim.x + threadIdx.x; i < E; i += stride) {
        int d = dst[i];
        unsigned r = (unsigned)atomicAdd(&cnt_in[d], 1);
        packed[i] = (r << 17) | (unsigned)d;
    }
}

// ---- 3-phase parallel exclusive scan of cnt_in -> row_ptr ----
__global__ __launch_bounds__(512)
void scan_local_kernel(const int* __restrict__ cnt_in,
                       int* __restrict__ row_ptr,
                       int* __restrict__ block_sums, int N) {
    __shared__ int tmp[512];
    const int t = threadIdx.x;
    const int gid = blockIdx.x * 512 + t;
    int v = (gid < N) ? cnt_in[gid] : 0;
    tmp[t] = v;
    __syncthreads();
    for (int off = 1; off < 512; off <<= 1) {
        int u = (t >= off) ? tmp[t - off] : 0;
        __syncthreads();
        tmp[t] += u;
        __syncthreads();
    }
    if (gid < N) row_ptr[gid] = tmp[t] - v;      // exclusive
    if (t == 511) block_sums[blockIdx.x] = tmp[511];
}

__global__ __launch_bounds__(1024)
void scan_sums_kernel(int* __restrict__ block_sums, int nb) {
    __shared__ int tmp[1024];
    const int t = threadIdx.x;
    int v = (t < nb) ? block_sums[t] : 0;
    tmp[t] = v;
    __syncthreads();
    for (int off = 1; off < 1024; off <<= 1) {
        int u = (t >= off) ? tmp[t - off] : 0;
        __syncthreads();
        tmp[t] += u;
        __syncthreads();
    }
    if (t < nb) block_sums[t] = tmp[t] - v;      // exclusive
}

__global__ __launch_bounds__(512)
void scan_add_kernel(int* __restrict__ row_ptr,
                     const int* __restrict__ block_sums, int N, int E) {
    const int gid = blockIdx.x * 512 + threadIdx.x;
    if (gid < N) row_ptr[gid] += block_sums[blockIdx.x];
    if (gid == 0) row_ptr[N] = E;
}

// Atomic-free CSR fill: slot = row_ptr[dst] + rank, both from packed word.
__global__ void fill_csr_kernel(const int* __restrict__ src,
                                const unsigned* __restrict__ packed,
                                const int* __restrict__ row_ptr,
                                int* __restrict__ csr_src, int E) {
    int stride = gridDim.x * blockDim.x;
    for (int i = blockIdx.x * blockDim.x + threadIdx.x; i < E; i += stride) {
        unsigned p = packed[i];
        csr_src[row_ptr[p & 0x1FFFFu] + (p >> 17)] = src[i];
    }
}

// Y[n][j] = (sum_k X[n][k] * W[k][j]) * rsqrt(max(cnt_out[n],1)), stored fp16.
// Block: 256 threads = 64 rows x 64 cols; thread computes 4 rows x 4 cols.
template <int K>
__global__ __launch_bounds__(256)
void gemm_scale_kernel(const float* __restrict__ X, const float* __restrict__ W,
                       const int* __restrict__ cnt_out,
                       __half* __restrict__ Y, int N) {
    __shared__ float Ws[K][64];
    const int t = threadIdx.x;
    for (int i = t; i < K * 64; i += 256) Ws[i >> 6][i & 63] = W[i];
    __syncthreads();

    const int cid = t & 15;            // cols 4*cid .. 4*cid+3
    const int rid = t >> 4;            // rows rowBase+4*rid .. +3
    const int rowBase = blockIdx.x * 64;

    const float* xp[4];
    int r[4];
#pragma unroll
    for (int i = 0; i < 4; ++i) {
        r[i] = rowBase + 4 * rid + i;
        xp[i] = X + (size_t)min(r[i], N - 1) * K;
    }

    float acc[4][4] = {};
#pragma unroll 2
    for (int kq = 0; kq < K / 4; ++kq) {
        const int k = kq * 4;
        float4 xv[4], wv[4];
#pragma unroll
        for (int i = 0; i < 4; ++i) xv[i] = *(const float4*)(xp[i] + k);
#pragma unroll
        for (int tt = 0; tt < 4; ++tt) wv[tt] = *(const float4*)&Ws[k + tt][4 * cid];
#pragma unroll
        for (int i = 0; i < 4; ++i) {
            const float* xf = (const float*)&xv[i];
#pragma unroll
            for (int tt = 0; tt < 4; ++tt) {
                const float a = xf[tt];
                const float* wf = (const float*)&wv[tt];
                acc[i][0] += a * wf[0];
                acc[i][1] += a * wf[1];
                acc[i][2] += a * wf[2];
                acc[i][3] += a * wf[3];
            }
        }
    }

#pragma unroll
    for (int i = 0; i < 4; ++i) {
        if (r[i] < N) {
            float sc = rsqrtf((float)max(cnt_out[r[i]], 1));
            __half2* yp = (__half2*)&Y[(size_t)r[i] * 64 + 4 * cid];
            yp[0] = __halves2half2(__float2half_rn(acc[i][0] * sc),
                                   __float2half_rn(acc[i][1] * sc));
            yp[1] = __halves2half2(__float2half_rn(acc[i][2] * sc),
                                   __float2half_rn(acc[i][3] * sc));
        }
    }
}

// out[n][f] = (sum_{in-edges} Y[src][f]) * rsqrt(max(cnt_in[n],1)) + bias[f]
// Wave = 1 node. Lanes 0-31: feature-pairs of edge e; lanes 32-63: edge e+1.
// Each lane loads __half2 (4 B) -> half the VMEM issue of the scalar version,
// 4 edges in flight per iteration. __shfl_xor(32) combines the two halves.
template <bool RELU>
__global__ __launch_bounds__(256)
void aggregate_kernel(const __half* __restrict__ Y,
                      const int* __restrict__ row_ptr,
                      const int* __restrict__ csr_src,
                      const int* __restrict__ cnt_in,
                      const float* __restrict__ bias,
                      float* __restrict__ out, int N) {
    const int lane = threadIdx.x & 63;
    const int n = blockIdx.x * 4 + (threadIdx.x >> 6);
    if (n >= N) return;
    const int half_id = lane >> 5;     // which edge of the pair
    const int fp = lane & 31;          // feature pair: feats 2*fp, 2*fp+1

    const int start = row_ptr[n];
    const int end   = row_ptr[n + 1];

    float2 acc = {0.f, 0.f};
    int e = start;
    for (; e + 4 <= end; e += 4) {     // 4 edges per iteration, 2 loads/lane
        int sa = csr_src[e + half_id];
        int sb = csr_src[e + 2 + half_id];
        float2 fa = __half22float2(*(const __half2*)&Y[(size_t)sa * 64 + 2 * fp]);
        float2 fb = __half22float2(*(const __half2*)&Y[(size_t)sb * 64 + 2 * fp]);
        acc.x += fa.x + fb.x;
        acc.y += fa.y + fb.y;
    }
    if (e + 2 <= end) {
        int sa = csr_src[e + half_id];
        float2 fa = __half22float2(*(const __half2*)&Y[(size_t)sa * 64 + 2 * fp]);
        acc.x += fa.x;
        acc.y += fa.y;
        e += 2;
    }
    if (e < end && half_id == 0) {     // single leftover edge
        float2 fa = __half22float2(*(const __half2*)&Y[(size_t)csr_src[e] * 64 + 2 * fp]);
        acc.x += fa.x;
        acc.y += fa.y;
    }

    acc.x += __shfl_xor(acc.x, 32);
    acc.y += __shfl_xor(acc.y, 32);

    if (half_id == 0) {
        float sc = rsqrtf((float)max(cnt_in[n], 1));
        float2 o;
        o.x = acc.x * sc + bias[2 * fp];
        o.y = acc.y * sc + bias[2 * fp + 1];
        if (RELU) { o.x = fmaxf(o.x, 0.f); o.y = fmaxf(o.y, 0.f); }
        *(float2*)&out[(size_t)n * 64 + 2 * fp] = o;
    }
}

extern "C" void kernel_launch(void* const* d_in, const int* in_sizes, int n_in,
                              void* d_out, int out_size, void* d_ws, size_t ws_size,
                              hipStream_t stream) {
    const float* x   = (const float*)d_in[0];
    const int*   src = (const int*)d_in[1];
    const int*   dst = (const int*)d_in[2];
    const float* W1  = (const float*)d_in[3];
    const float* b1  = (const float*)d_in[4];
    const float* W2  = (const float*)d_in[5];
    const float* b2  = (const float*)d_in[6];
    float* out = (float*)d_out;

    const int N = in_sizes[0] / 128;   // 100000
    const int E = in_sizes[1];         // 1600000

    const int SCAN_B = 512;
    const int nb = (N + SCAN_B - 1) / SCAN_B;   // 196 blocks

    // Workspace (~40 MB). partial_src [64][N] ints (25.6 MB) is time-shared
    // with Y fp16 (12.8 MB). d_out doubles as the hidden-layer buffer.
    char* ws = (char*)d_ws;
    size_t off = 0;
    int*      partial_src = (int*)(ws + off); off = align256(off + (size_t)HIST_SLICES * N * sizeof(int));
    int*      csr_src     = (int*)(ws + off); off = align256(off + (size_t)E * sizeof(int));
    unsigned* packed      = (unsigned*)(ws + off); off = align256(off + (size_t)E * sizeof(unsigned));
    int*      cnt_out     = (int*)(ws + off); off = align256(off + (size_t)N * sizeof(int));
    int*      cnt_in      = (int*)(ws + off); off = align256(off + (size_t)N * sizeof(int));
    int*      row_ptr     = (int*)(ws + off); off = align256(off + (size_t)(N + 1) * sizeof(int));
    int*      blk_sums    = (int*)(ws + off); off = align256(off + (size_t)nb * sizeof(int));

    __half* Y = (__half*)partial_src;     // fp16 projected features (time-shared)

    const int slice_len = (E + HIST_SLICES - 1) / HIST_SLICES;
    const int nbins = (N + HIST_BIN - 1) / HIST_BIN;

    hipMemsetAsync(cnt_in, 0, (size_t)N * sizeof(int), stream);

    // cnt_out histogram (no device atomics)
    hist_partial_kernel<<<dim3(HIST_SLICES, nbins), 256, 0, stream>>>(src, partial_src, N, E, slice_len);
    hist_reduce_kernel<<<(N + 255) / 256, 256, 0, stream>>>(partial_src, cnt_out, N);

    // cnt_in + packed ranks (1.6M device atomics), scan, CSR fill
    rank_kernel<<<2048, 256, 0, stream>>>(dst, cnt_in, packed, E);
    scan_local_kernel<<<nb, SCAN_B, 0, stream>>>(cnt_in, row_ptr, blk_sums, N);
    scan_sums_kernel<<<1, 1024, 0, stream>>>(blk_sums, nb);
    scan_add_kernel<<<nb, SCAN_B, 0, stream>>>(row_ptr, blk_sums, N, E);
    fill_csr_kernel<<<2048, 256, 0, stream>>>(src, packed, row_ptr, csr_src, E);

    const int gemm_blocks = (N + 63) / 64;   // 64 rows per block
    const int agg_blocks  = (N + 3) / 4;     // 4 nodes per block

    // Layer 1: Y = fp16[(X @ W1) * rs_out] ; agg -> d_out (hidden, relu)
    gemm_scale_kernel<128><<<gemm_blocks, 256, 0, stream>>>(x, W1, cnt_out, Y, N);
    aggregate_kernel<true><<<agg_blocks, 256, 0, stream>>>(Y, row_ptr, csr_src, cnt_in, b1, out, N);

    // Layer 2: Y = fp16[(H @ W2) * rs_out] ; agg -> d_out (final)
    gemm_scale_kernel<64><<<gemm_blocks, 256, 0, stream>>>(out, W2, cnt_out, Y, N);
    aggregate_kernel<false><<<agg_blocks, 256, 0, stream>>>(Y, row_ptr, csr_src, cnt_in, b2, out, N);
}

// Round 8
// 367.729 us; speedup vs baseline: 1.4129x; 1.1363x over previous
//
#include <hip/hip_runtime.h>
#include <hip/hip_fp16.h>

// GCN 2-layer: out = D_in^-1/2 A D_out^-1/2 (relu(D_in^-1/2 A D_out^-1/2 X W1 + b1)) W2 + b2
// Strategy: project-then-aggregate (matmul commutes with segment_sum),
// CSR-by-dst built per call.
// R1: parallel scan. R2: register-tiled GEMM. R4: LDS histograms + fp16 Y.
// R5 FAILED: binned scatter at 16% occupancy. R6: atomic ranks = 67 us floor
// (device atomic pipe ~24 G/s). R7: radix-partition CSR build — per-block
// bucket histograms (dst>>7) -> scan [bucket][block] -> LDS-cursor partition
// scatter (packed (local<<17|src)) -> per-bucket finalize emits cnt_in,
// row_ptr, csr_src. ZERO device atomics, all high-occupancy, each edge O(1)
// reads. Aggregate unrolled to 8 edges/iter (latency-bound gather).

static inline size_t align256(size_t x) { return (x + 255) & ~(size_t)255; }

#define HIST_BIN 8192
#define HIST_SLICES 64

#define BKT_SHIFT 7
#define BKT_W 128              // nodes per bucket window
#define MAX_NBK 800            // LDS sizing guard (N <= 102400)
#define PA_BLOCKS 416          // partition pass blocks

// ---- cnt_out (out-degree) via binned LDS histogram ----
__global__ __launch_bounds__(256)
void hist_partial_kernel(const int* __restrict__ keys,
                         int* __restrict__ partial,   // [HIST_SLICES][N]
                         int N, int E, int slice_len) {
    __shared__ int h[HIST_BIN];
    const int s = blockIdx.x;
    const int lo = blockIdx.y * HIST_BIN;
    for (int i = threadIdx.x; i < HIST_BIN; i += 256) h[i] = 0;
    __syncthreads();
    const int beg = s * slice_len;
    const int end = min(beg + slice_len, E);
    for (int i = beg + threadIdx.x; i < end; i += 256) {
        int v = keys[i] - lo;
        if ((unsigned)v < (unsigned)HIST_BIN) atomicAdd(&h[v], 1);  // LDS atomic
    }
    __syncthreads();
    const int hi = min(lo + HIST_BIN, N);
    int* p = partial + (size_t)s * N;
    for (int v = lo + threadIdx.x; v < hi; v += 256) p[v] = h[v - lo];
}

__global__ void hist_reduce_kernel(const int* __restrict__ partial,
                                   int* __restrict__ cnt, int N) {
    const int v = blockIdx.x * 256 + threadIdx.x;
    if (v >= N) return;
    int sum = 0;
#pragma unroll 4
    for (int s = 0; s < HIST_SLICES; ++s) sum += partial[(size_t)s * N + v];
    cnt[v] = sum;
}

// ---- Radix partition of edges by dst bucket (dst >> BKT_SHIFT) ----
// A1: per-block bucket histogram -> hist_g[bucket][block] (bin-major).
__global__ __launch_bounds__(256)
void part_hist_kernel(const int* __restrict__ dst,
                      int* __restrict__ hist_g, int nbk, int E, int slice_len) {
    __shared__ int h[MAX_NBK];
    const int b = blockIdx.x;
    for (int i = threadIdx.x; i < nbk; i += 256) h[i] = 0;
    __syncthreads();
    const int beg = b * slice_len;
    const int end = min(beg + slice_len, E);
    for (int i = beg + threadIdx.x; i < end; i += 256)
        atomicAdd(&h[dst[i] >> BKT_SHIFT], 1);                      // LDS atomic
    __syncthreads();
    for (int i = threadIdx.x; i < nbk; i += 256)
        hist_g[(size_t)i * PA_BLOCKS + b] = h[i];
}

// ---- generic 3-phase exclusive scan (in: data, out: data in-place) ----
__global__ __launch_bounds__(512)
void scan_local_kernel(int* __restrict__ data,
                       int* __restrict__ block_sums, int M) {
    __shared__ int tmp[512];
    const int t = threadIdx.x;
    const int gid = blockIdx.x * 512 + t;
    int v = (gid < M) ? data[gid] : 0;
    tmp[t] = v;
    __syncthreads();
    for (int off = 1; off < 512; off <<= 1) {
        int u = (t >= off) ? tmp[t - off] : 0;
        __syncthreads();
        tmp[t] += u;
        __syncthreads();
    }
    if (gid < M) data[gid] = tmp[t] - v;         // exclusive
    if (t == 511) block_sums[blockIdx.x] = tmp[511];
}

__global__ __launch_bounds__(1024)
void scan_sums_kernel(int* __restrict__ block_sums, int nb) {
    __shared__ int tmp[1024];
    const int t = threadIdx.x;
    int v = (t < nb) ? block_sums[t] : 0;
    tmp[t] = v;
    __syncthreads();
    for (int off = 1; off < 1024; off <<= 1) {
        int u = (t >= off) ? tmp[t - off] : 0;
        __syncthreads();
        tmp[t] += u;
        __syncthreads();
    }
    if (t < nb) block_sums[t] = tmp[t] - v;      // exclusive
}

__global__ __launch_bounds__(512)
void scan_add_kernel(int* __restrict__ data,
                     const int* __restrict__ block_sums, int M) {
    const int gid = blockIdx.x * 512 + threadIdx.x;
    if (gid < M) data[gid] += block_sums[blockIdx.x];
}

// A2: partition scatter. Each block loads its 782 cursors from the scanned
// table, then writes each edge (packed local<<17|src) to a unique slot.
__global__ __launch_bounds__(256)
void part_scatter_kernel(const int* __restrict__ src,
                         const int* __restrict__ dst,
                         const int* __restrict__ base,   // scanned [nbk][PA_BLOCKS]
                         int* __restrict__ ebuf,
                         int nbk, int E, int slice_len) {
    __shared__ int cur[MAX_NBK];
    const int b = blockIdx.x;
    for (int i = threadIdx.x; i < nbk; i += 256)
        cur[i] = base[(size_t)i * PA_BLOCKS + b];
    __syncthreads();
    const int beg = b * slice_len;
    const int end = min(beg + slice_len, E);
    for (int i = beg + threadIdx.x; i < end; i += 256) {
        int d = dst[i];
        int pos = atomicAdd(&cur[d >> BKT_SHIFT], 1);               // LDS atomic
        ebuf[pos] = ((d & (BKT_W - 1)) << 17) | src[i];
    }
}

// B: per-bucket finalize. Block k owns nodes [k*128, ...) and the contiguous
// edge segment [base[k][0], base[k+1][0]). Emits cnt_in, row_ptr, csr_src.
__global__ __launch_bounds__(256)
void bucket_csr_kernel(const int* __restrict__ ebuf,
                       const int* __restrict__ base,
                       int* __restrict__ csr_src,
                       int* __restrict__ cnt_in,
                       int* __restrict__ row_ptr,
                       int nbk, int N, int E) {
    __shared__ int cnt[BKT_W];
    __shared__ int rp[BKT_W];
    const int k = blockIdx.x;
    const int lo = k << BKT_SHIFT;
    const int span = min(BKT_W, N - lo);
    const int segbeg = base[(size_t)k * PA_BLOCKS];
    const int segend = (k == nbk - 1) ? E : base[(size_t)(k + 1) * PA_BLOCKS];
    const int t = threadIdx.x;

    if (t < BKT_W) cnt[t] = 0;
    __syncthreads();
    for (int i = segbeg + t; i < segend; i += 256)
        atomicAdd(&cnt[ebuf[i] >> 17], 1);                          // LDS atomic
    __syncthreads();
    // exclusive scan of cnt into (rp - cnt): Hillis-Steele over 128
    if (t < BKT_W) rp[t] = cnt[t];
    __syncthreads();
    for (int off = 1; off < BKT_W; off <<= 1) {
        int v = (t < BKT_W && t >= off) ? rp[t - off] : 0;
        __syncthreads();
        if (t < BKT_W) rp[t] += v;
        __syncthreads();
    }
    if (t < span) {
        int rbase = segbeg + rp[t] - cnt[t];
        row_ptr[lo + t] = rbase;
        cnt_in[lo + t]  = cnt[t];
    }
    __syncthreads();
    if (t < BKT_W) cnt[t] = segbeg + rp[t] - cnt[t];   // reuse as global cursor
    __syncthreads();
    for (int i = segbeg + t; i < segend; i += 256) {
        int p = ebuf[i];
        int pos = atomicAdd(&cnt[p >> 17], 1);                      // LDS atomic
        csr_src[pos] = p & 0x1FFFF;
    }
    if (k == 0 && t == 0) row_ptr[N] = E;
}

// Y[n][j] = (sum_k X[n][k] * W[k][j]) * rsqrt(max(cnt_out[n],1)), stored fp16.
// Block: 256 threads = 64 rows x 64 cols; thread computes 4 rows x 4 cols.
template <int K>
__global__ __launch_bounds__(256)
void gemm_scale_kernel(const float* __restrict__ X, const float* __restrict__ W,
                       const int* __restrict__ cnt_out,
                       __half* __restrict__ Y, int N) {
    __shared__ float Ws[K][64];
    const int t = threadIdx.x;
    for (int i = t; i < K * 64; i += 256) Ws[i >> 6][i & 63] = W[i];
    __syncthreads();

    const int cid = t & 15;
    const int rid = t >> 4;
    const int rowBase = blockIdx.x * 64;

    const float* xp[4];
    int r[4];
#pragma unroll
    for (int i = 0; i < 4; ++i) {
        r[i] = rowBase + 4 * rid + i;
        xp[i] = X + (size_t)min(r[i], N - 1) * K;
    }

    float acc[4][4] = {};
#pragma unroll 2
    for (int kq = 0; kq < K / 4; ++kq) {
        const int k = kq * 4;
        float4 xv[4], wv[4];
#pragma unroll
        for (int i = 0; i < 4; ++i) xv[i] = *(const float4*)(xp[i] + k);
#pragma unroll
        for (int tt = 0; tt < 4; ++tt) wv[tt] = *(const float4*)&Ws[k + tt][4 * cid];
#pragma unroll
        for (int i = 0; i < 4; ++i) {
            const float* xf = (const float*)&xv[i];
#pragma unroll
            for (int tt = 0; tt < 4; ++tt) {
                const float a = xf[tt];
                const float* wf = (const float*)&wv[tt];
                acc[i][0] += a * wf[0];
                acc[i][1] += a * wf[1];
                acc[i][2] += a * wf[2];
                acc[i][3] += a * wf[3];
            }
        }
    }

#pragma unroll
    for (int i = 0; i < 4; ++i) {
        if (r[i] < N) {
            float sc = rsqrtf((float)max(cnt_out[r[i]], 1));
            __half2* yp = (__half2*)&Y[(size_t)r[i] * 64 + 4 * cid];
            yp[0] = __halves2half2(__float2half_rn(acc[i][0] * sc),
                                   __float2half_rn(acc[i][1] * sc));
            yp[1] = __halves2half2(__float2half_rn(acc[i][2] * sc),
                                   __float2half_rn(acc[i][3] * sc));
        }
    }
}

// out[n][f] = (sum_{in-edges} Y[src][f]) * rsqrt(max(cnt_in[n],1)) + bias[f]
// Wave = 1 node; lanes 0-31 / 32-63 split edge pairs; half2 feature loads.
// Unroll 8 edges/iter -> 4 Y-loads in flight per lane (latency-bound gather).
template <bool RELU>
__global__ __launch_bounds__(256)
void aggregate_kernel(const __half* __restrict__ Y,
                      const int* __restrict__ row_ptr,
                      const int* __restrict__ csr_src,
                      const int* __restrict__ cnt_in,
                      const float* __restrict__ bias,
                      float* __restrict__ out, int N) {
    const int lane = threadIdx.x & 63;
    const int n = blockIdx.x * 4 + (threadIdx.x >> 6);
    if (n >= N) return;
    const int half_id = lane >> 5;
    const int fp = lane & 31;

    const int start = row_ptr[n];
    const int end   = row_ptr[n + 1];

    float2 acc = {0.f, 0.f};
    int e = start;
    for (; e + 8 <= end; e += 8) {     // 8 edges per iteration, 4 loads/lane
        int s0 = csr_src[e + half_id];
        int s1 = csr_src[e + 2 + half_id];
        int s2 = csr_src[e + 4 + half_id];
        int s3 = csr_src[e + 6 + half_id];
        float2 f0 = __half22float2(*(const __half2*)&Y[(size_t)s0 * 64 + 2 * fp]);
        float2 f1 = __half22float2(*(const __half2*)&Y[(size_t)s1 * 64 + 2 * fp]);
        float2 f2 = __half22float2(*(const __half2*)&Y[(size_t)s2 * 64 + 2 * fp]);
        float2 f3 = __half22float2(*(const __half2*)&Y[(size_t)s3 * 64 + 2 * fp]);
        acc.x += f0.x + f1.x + f2.x + f3.x;
        acc.y += f0.y + f1.y + f2.y + f3.y;
    }
    for (; e + 2 <= end; e += 2) {
        int s = csr_src[e + half_id];
        float2 f = __half22float2(*(const __half2*)&Y[(size_t)s * 64 + 2 * fp]);
        acc.x += f.x;
        acc.y += f.y;
    }
    if (e < end && half_id == 0) {
        float2 f = __half22float2(*(const __half2*)&Y[(size_t)csr_src[e] * 64 + 2 * fp]);
        acc.x += f.x;
        acc.y += f.y;
    }

    acc.x += __shfl_xor(acc.x, 32);
    acc.y += __shfl_xor(acc.y, 32);

    if (half_id == 0) {
        float sc = rsqrtf((float)max(cnt_in[n], 1));
        float2 o;
        o.x = acc.x * sc + bias[2 * fp];
        o.y = acc.y * sc + bias[2 * fp + 1];
        if (RELU) { o.x = fmaxf(o.x, 0.f); o.y = fmaxf(o.y, 0.f); }
        *(float2*)&out[(size_t)n * 64 + 2 * fp] = o;
    }
}

extern "C" void kernel_launch(void* const* d_in, const int* in_sizes, int n_in,
                              void* d_out, int out_size, void* d_ws, size_t ws_size,
                              hipStream_t stream) {
    const float* x   = (const float*)d_in[0];
    const int*   src = (const int*)d_in[1];
    const int*   dst = (const int*)d_in[2];
    const float* W1  = (const float*)d_in[3];
    const float* b1  = (const float*)d_in[4];
    const float* W2  = (const float*)d_in[5];
    const float* b2  = (const float*)d_in[6];
    float* out = (float*)d_out;

    const int N = in_sizes[0] / 128;   // 100000
    const int E = in_sizes[1];         // 1600000

    const int nbk = (N + BKT_W - 1) >> BKT_SHIFT;          // 782 buckets
    const int M = nbk * PA_BLOCKS;                         // scan size
    const int nbM = (M + 511) / 512;                       // <= 1024

    // Workspace (~42 MB). partial_src [64][N] ints (25.6 MB) time-shared with
    // Y fp16 (12.8 MB). d_out doubles as the hidden-layer buffer.
    char* ws = (char*)d_ws;
    size_t off = 0;
    int* partial_src = (int*)(ws + off); off = align256(off + (size_t)HIST_SLICES * N * sizeof(int));
    int* csr_src     = (int*)(ws + off); off = align256(off + (size_t)E * sizeof(int));
    int* ebuf        = (int*)(ws + off); off = align256(off + (size_t)E * sizeof(int));
    int* hist_g      = (int*)(ws + off); off = align256(off + (size_t)M * sizeof(int));
    int* cnt_out     = (int*)(ws + off); off = align256(off + (size_t)N * sizeof(int));
    int* cnt_in      = (int*)(ws + off); off = align256(off + (size_t)N * sizeof(int));
    int* row_ptr     = (int*)(ws + off); off = align256(off + (size_t)(N + 1) * sizeof(int));
    int* blk_sums    = (int*)(ws + off); off = align256(off + (size_t)nbM * sizeof(int));

    __half* Y = (__half*)partial_src;     // fp16 projected features (time-shared)

    const int hslice = (E + HIST_SLICES - 1) / HIST_SLICES;
    const int nbins = (N + HIST_BIN - 1) / HIST_BIN;
    const int pslice = (E + PA_BLOCKS - 1) / PA_BLOCKS;

    // cnt_out histogram (independent of CSR build)
    hist_partial_kernel<<<dim3(HIST_SLICES, nbins), 256, 0, stream>>>(src, partial_src, N, E, hslice);
    hist_reduce_kernel<<<(N + 255) / 256, 256, 0, stream>>>(partial_src, cnt_out, N);

    // Radix-partition CSR build (zero device atomics)
    part_hist_kernel<<<PA_BLOCKS, 256, 0, stream>>>(dst, hist_g, nbk, E, pslice);
    scan_local_kernel<<<nbM, 512, 0, stream>>>(hist_g, blk_sums, M);
    scan_sums_kernel<<<1, 1024, 0, stream>>>(blk_sums, nbM);
    scan_add_kernel<<<nbM, 512, 0, stream>>>(hist_g, blk_sums, M);
    part_scatter_kernel<<<PA_BLOCKS, 256, 0, stream>>>(src, dst, hist_g, ebuf, nbk, E, pslice);
    bucket_csr_kernel<<<nbk, 256, 0, stream>>>(ebuf, hist_g, csr_src, cnt_in, row_ptr, nbk, N, E);

    const int gemm_blocks = (N + 63) / 64;
    const int agg_blocks  = (N + 3) / 4;

    // Layer 1: Y = fp16[(X @ W1) * rs_out] ; agg -> d_out (hidden, relu)
    gemm_scale_kernel<128><<<gemm_blocks, 256, 0, stream>>>(x, W1, cnt_out, Y, N);
    aggregate_kernel<true><<<agg_blocks, 256, 0, stream>>>(Y, row_ptr, csr_src, cnt_in, b1, out, N);

    // Layer 2: Y = fp16[(H @ W2) * rs_out] ; agg -> d_out (final)
    gemm_scale_kernel<64><<<gemm_blocks, 256, 0, stream>>>(out, W2, cnt_out, Y, N);
    aggregate_kernel<false><<<agg_blocks, 256, 0, stream>>>(Y, row_ptr, csr_src, cnt_in, b2, out, N);
}

// Round 9
// 356.395 us; speedup vs baseline: 1.4578x; 1.0318x over previous
//
#include <hip/hip_runtime.h>
#include <hip/hip_fp16.h>

// GCN 2-layer: out = D_in^-1/2 A D_out^-1/2 (relu(D_in^-1/2 A D_out^-1/2 X W1 + b1)) W2 + b2
// Strategy: project-then-aggregate; CSR-by-dst via radix partition, zero
// device-scope atomics anywhere.
// R2: register-tiled GEMM. R4: fp16 Y. R6: atomic-rank floor = 67us.
// R7: radix-partition CSR (dst>>7 buckets, LDS cursors). 368 us.
// R8: DUAL partition — same kernels also bucket src>>7 and emit cnt_out from
//     a 1-byte sbuf, deleting the 13x-reread histogram pair (~50 us) and the
//     memset; scan chain restructured to per-row prefix + total scan
//     (12 -> 9 dispatches). Aggregate unrolled to 16 edges/iter.

static inline size_t align256(size_t x) { return (x + 255) & ~(size_t)255; }

#define BKT_SHIFT 7
#define BKT_W 128              // nodes per bucket window
#define MAX_NBK 800            // LDS sizing guard (N <= 102400)
#define PA_BLOCKS 416          // partition pass blocks

// A1: per-block bucket histograms of BOTH dst>>7 and src>>7.
__global__ __launch_bounds__(256)
void part_hist_kernel(const int* __restrict__ src, const int* __restrict__ dst,
                      int* __restrict__ hist_d, int* __restrict__ hist_s,
                      int nbk, int E, int slice_len) {
    __shared__ int hd[MAX_NBK];
    __shared__ int hs[MAX_NBK];
    const int b = blockIdx.x;
    for (int i = threadIdx.x; i < nbk; i += 256) { hd[i] = 0; hs[i] = 0; }
    __syncthreads();
    const int beg = b * slice_len;
    const int end = min(beg + slice_len, E);
    for (int i = beg + threadIdx.x; i < end; i += 256) {
        atomicAdd(&hd[dst[i] >> BKT_SHIFT], 1);   // LDS atomics
        atomicAdd(&hs[src[i] >> BKT_SHIFT], 1);
    }
    __syncthreads();
    for (int i = threadIdx.x; i < nbk; i += 256) {
        hist_d[(size_t)i * PA_BLOCKS + b] = hd[i];
        hist_s[(size_t)i * PA_BLOCKS + b] = hs[i];
    }
}

// A2: per-bucket-row exclusive prefix over the PA_BLOCKS counts (in place),
// row total out. Grid = 2*nbk blocks (dst rows then src rows).
__global__ __launch_bounds__(512)
void row_scan_kernel(int* __restrict__ hist_d, int* __restrict__ hist_s,
                     int* __restrict__ Td, int* __restrict__ Ts, int nbk) {
    __shared__ int tmp[512];
    int j = blockIdx.x;
    int* row;
    int* T;
    if (j < nbk) { row = hist_d + (size_t)j * PA_BLOCKS; T = Td; }
    else         { j -= nbk; row = hist_s + (size_t)j * PA_BLOCKS; T = Ts; }
    const int t = threadIdx.x;
    int v = (t < PA_BLOCKS) ? row[t] : 0;
    tmp[t] = v;
    __syncthreads();
    for (int off = 1; off < 512; off <<= 1) {
        int u = (t >= off) ? tmp[t - off] : 0;
        __syncthreads();
        tmp[t] += u;
        __syncthreads();
    }
    if (t < PA_BLOCKS) row[t] = tmp[t] - v;      // exclusive within row
    if (t == 511) T[j] = tmp[511];               // row total
}

// A3: exclusive scan of the bucket totals (both tables), in place.
__global__ __launch_bounds__(1024)
void tot_scan_kernel(int* __restrict__ Td, int* __restrict__ Ts, int nbk) {
    __shared__ int tmp[1024];
    const int t = threadIdx.x;
    int v = (t < nbk) ? Td[t] : 0;
    tmp[t] = v;
    __syncthreads();
    for (int off = 1; off < 1024; off <<= 1) {
        int u = (t >= off) ? tmp[t - off] : 0;
        __syncthreads();
        tmp[t] += u;
        __syncthreads();
    }
    if (t < nbk) Td[t] = tmp[t] - v;
    __syncthreads();
    int v2 = (t < nbk) ? Ts[t] : 0;
    tmp[t] = v2;
    __syncthreads();
    for (int off = 1; off < 1024; off <<= 1) {
        int u = (t >= off) ? tmp[t - off] : 0;
        __syncthreads();
        tmp[t] += u;
        __syncthreads();
    }
    if (t < nbk) Ts[t] = tmp[t] - v2;
}

// A4: partition scatter. ebuf gets (dst&127)<<17 | src (dst-bucketed);
// sbuf gets 1-byte src&127 (src-bucketed) for the cnt_out count.
__global__ __launch_bounds__(256)
void part_scatter_kernel(const int* __restrict__ src, const int* __restrict__ dst,
                         const int* __restrict__ hist_d, const int* __restrict__ hist_s,
                         const int* __restrict__ Td, const int* __restrict__ Ts,
                         int* __restrict__ ebuf, unsigned char* __restrict__ sbuf,
                         int nbk, int E, int slice_len) {
    __shared__ int cur_d[MAX_NBK];
    __shared__ int cur_s[MAX_NBK];
    const int b = blockIdx.x;
    for (int i = threadIdx.x; i < nbk; i += 256) {
        cur_d[i] = Td[i] + hist_d[(size_t)i * PA_BLOCKS + b];
        cur_s[i] = Ts[i] + hist_s[(size_t)i * PA_BLOCKS + b];
    }
    __syncthreads();
    const int beg = b * slice_len;
    const int end = min(beg + slice_len, E);
    for (int i = beg + threadIdx.x; i < end; i += 256) {
        int d = dst[i], s = src[i];
        int pd = atomicAdd(&cur_d[d >> BKT_SHIFT], 1);   // LDS atomic
        ebuf[pd] = ((d & (BKT_W - 1)) << 17) | s;
        int ps = atomicAdd(&cur_s[s >> BKT_SHIFT], 1);   // LDS atomic
        sbuf[ps] = (unsigned char)(s & (BKT_W - 1));
    }
}

// B: per-bucket finalize. Emits cnt_in, cnt_out, row_ptr, csr_src.
__global__ __launch_bounds__(256)
void bucket_csr_kernel(const int* __restrict__ ebuf,
                       const unsigned char* __restrict__ sbuf,
                       const int* __restrict__ Td, const int* __restrict__ Ts,
                       int* __restrict__ csr_src,
                       int* __restrict__ cnt_in, int* __restrict__ cnt_out,
                       int* __restrict__ row_ptr,
                       int nbk, int N, int E) {
    __shared__ int cnt[BKT_W];
    __shared__ int rp[BKT_W];
    __shared__ int cur[BKT_W];
    __shared__ int cnts[BKT_W];
    const int k = blockIdx.x;
    const int lo = k << BKT_SHIFT;
    const int span = min(BKT_W, N - lo);
    const int db = Td[k], de = (k + 1 < nbk) ? Td[k + 1] : E;
    const int sb = Ts[k], se = (k + 1 < nbk) ? Ts[k + 1] : E;
    const int t = threadIdx.x;

    if (t < BKT_W) { cnt[t] = 0; cnts[t] = 0; }
    __syncthreads();
    for (int i = db + t; i < de; i += 256) atomicAdd(&cnt[ebuf[i] >> 17], 1);
    for (int i = sb + t; i < se; i += 256) atomicAdd(&cnts[sbuf[i]], 1);
    __syncthreads();
    if (t < BKT_W) rp[t] = cnt[t];
    __syncthreads();
    for (int off = 1; off < BKT_W; off <<= 1) {
        int v = (t < BKT_W && t >= off) ? rp[t - off] : 0;
        __syncthreads();
        if (t < BKT_W) rp[t] += v;
        __syncthreads();
    }
    if (t < span) {
        row_ptr[lo + t] = db + rp[t] - cnt[t];
        cnt_in[lo + t]  = cnt[t];
        cnt_out[lo + t] = cnts[t];
    }
    __syncthreads();
    if (t < BKT_W) cur[t] = db + rp[t] - cnt[t];
    __syncthreads();
    for (int i = db + t; i < de; i += 256) {
        int p = ebuf[i];
        int pos = atomicAdd(&cur[p >> 17], 1);           // LDS atomic
        csr_src[pos] = p & 0x1FFFF;
    }
    if (k == 0 && t == 0) row_ptr[N] = E;
}

// Y[n][j] = (sum_k X[n][k] * W[k][j]) * rsqrt(max(cnt_out[n],1)), stored fp16.
template <int K>
__global__ __launch_bounds__(256)
void gemm_scale_kernel(const float* __restrict__ X, const float* __restrict__ W,
                       const int* __restrict__ cnt_out,
                       __half* __restrict__ Y, int N) {
    __shared__ float Ws[K][64];
    const int t = threadIdx.x;
    for (int i = t; i < K * 64; i += 256) Ws[i >> 6][i & 63] = W[i];
    __syncthreads();

    const int cid = t & 15;
    const int rid = t >> 4;
    const int rowBase = blockIdx.x * 64;

    const float* xp[4];
    int r[4];
#pragma unroll
    for (int i = 0; i < 4; ++i) {
        r[i] = rowBase + 4 * rid + i;
        xp[i] = X + (size_t)min(r[i], N - 1) * K;
    }

    float acc[4][4] = {};
#pragma unroll 2
    for (int kq = 0; kq < K / 4; ++kq) {
        const int k = kq * 4;
        float4 xv[4], wv[4];
#pragma unroll
        for (int i = 0; i < 4; ++i) xv[i] = *(const float4*)(xp[i] + k);
#pragma unroll
        for (int tt = 0; tt < 4; ++tt) wv[tt] = *(const float4*)&Ws[k + tt][4 * cid];
#pragma unroll
        for (int i = 0; i < 4; ++i) {
            const float* xf = (const float*)&xv[i];
#pragma unroll
            for (int tt = 0; tt < 4; ++tt) {
                const float a = xf[tt];
                const float* wf = (const float*)&wv[tt];
                acc[i][0] += a * wf[0];
                acc[i][1] += a * wf[1];
                acc[i][2] += a * wf[2];
                acc[i][3] += a * wf[3];
            }
        }
    }

#pragma unroll
    for (int i = 0; i < 4; ++i) {
        if (r[i] < N) {
            float sc = rsqrtf((float)max(cnt_out[r[i]], 1));
            __half2* yp = (__half2*)&Y[(size_t)r[i] * 64 + 4 * cid];
            yp[0] = __halves2half2(__float2half_rn(acc[i][0] * sc),
                                   __float2half_rn(acc[i][1] * sc));
            yp[1] = __halves2half2(__float2half_rn(acc[i][2] * sc),
                                   __float2half_rn(acc[i][3] * sc));
        }
    }
}

// out[n][f] = (sum_{in-edges} Y[src][f]) * rsqrt(max(cnt_in[n],1)) + bias[f]
// Wave = 1 node; lanes split edge pairs; half2 loads; 16 edges/iter
// (8 gathers in flight per lane — latency-bound L2/L3 gather).
template <bool RELU>
__global__ __launch_bounds__(256)
void aggregate_kernel(const __half* __restrict__ Y,
                      const int* __restrict__ row_ptr,
                      const int* __restrict__ csr_src,
                      const int* __restrict__ cnt_in,
                      const float* __restrict__ bias,
                      float* __restrict__ out, int N) {
    const int lane = threadIdx.x & 63;
    const int n = blockIdx.x * 4 + (threadIdx.x >> 6);
    if (n >= N) return;
    const int half_id = lane >> 5;
    const int fp = lane & 31;

    const int start = row_ptr[n];
    const int end   = row_ptr[n + 1];

    float2 acc = {0.f, 0.f};
    int e = start;
    for (; e + 16 <= end; e += 16) {   // 16 edges/iter, 8 loads/lane
        int s0 = csr_src[e + half_id];
        int s1 = csr_src[e + 2 + half_id];
        int s2 = csr_src[e + 4 + half_id];
        int s3 = csr_src[e + 6 + half_id];
        int s4 = csr_src[e + 8 + half_id];
        int s5 = csr_src[e + 10 + half_id];
        int s6 = csr_src[e + 12 + half_id];
        int s7 = csr_src[e + 14 + half_id];
        float2 f0 = __half22float2(*(const __half2*)&Y[(size_t)s0 * 64 + 2 * fp]);
        float2 f1 = __half22float2(*(const __half2*)&Y[(size_t)s1 * 64 + 2 * fp]);
        float2 f2 = __half22float2(*(const __half2*)&Y[(size_t)s2 * 64 + 2 * fp]);
        float2 f3 = __half22float2(*(const __half2*)&Y[(size_t)s3 * 64 + 2 * fp]);
        float2 f4 = __half22float2(*(const __half2*)&Y[(size_t)s4 * 64 + 2 * fp]);
        float2 f5 = __half22float2(*(const __half2*)&Y[(size_t)s5 * 64 + 2 * fp]);
        float2 f6 = __half22float2(*(const __half2*)&Y[(size_t)s6 * 64 + 2 * fp]);
        float2 f7 = __half22float2(*(const __half2*)&Y[(size_t)s7 * 64 + 2 * fp]);
        acc.x += f0.x + f1.x + f2.x + f3.x + f4.x + f5.x + f6.x + f7.x;
        acc.y += f0.y + f1.y + f2.y + f3.y + f4.y + f5.y + f6.y + f7.y;
    }
    for (; e + 2 <= end; e += 2) {
        int s = csr_src[e + half_id];
        float2 f = __half22float2(*(const __half2*)&Y[(size_t)s * 64 + 2 * fp]);
        acc.x += f.x;
        acc.y += f.y;
    }
    if (e < end && half_id == 0) {
        float2 f = __half22float2(*(const __half2*)&Y[(size_t)csr_src[e] * 64 + 2 * fp]);
        acc.x += f.x;
        acc.y += f.y;
    }

    acc.x += __shfl_xor(acc.x, 32);
    acc.y += __shfl_xor(acc.y, 32);

    if (half_id == 0) {
        float sc = rsqrtf((float)max(cnt_in[n], 1));
        float2 o;
        o.x = acc.x * sc + bias[2 * fp];
        o.y = acc.y * sc + bias[2 * fp + 1];
        if (RELU) { o.x = fmaxf(o.x, 0.f); o.y = fmaxf(o.y, 0.f); }
        *(float2*)&out[(size_t)n * 64 + 2 * fp] = o;
    }
}

extern "C" void kernel_launch(void* const* d_in, const int* in_sizes, int n_in,
                              void* d_out, int out_size, void* d_ws, size_t ws_size,
                              hipStream_t stream) {
    const float* x   = (const float*)d_in[0];
    const int*   src = (const int*)d_in[1];
    const int*   dst = (const int*)d_in[2];
    const float* W1  = (const float*)d_in[3];
    const float* b1  = (const float*)d_in[4];
    const float* W2  = (const float*)d_in[5];
    const float* b2  = (const float*)d_in[6];
    float* out = (float*)d_out;

    const int N = in_sizes[0] / 128;   // 100000
    const int E = in_sizes[1];         // 1600000

    const int nbk = (N + BKT_W - 1) >> BKT_SHIFT;          // 782 buckets
    const int M = nbk * PA_BLOCKS;

    // Workspace (~30 MB). d_out doubles as the hidden-layer buffer.
    char* ws = (char*)d_ws;
    size_t off = 0;
    __half* Y       = (__half*)(ws + off); off = align256(off + (size_t)N * 64 * sizeof(__half));
    int* csr_src    = (int*)(ws + off);    off = align256(off + (size_t)E * sizeof(int));
    int* ebuf       = (int*)(ws + off);    off = align256(off + (size_t)E * sizeof(int));
    unsigned char* sbuf = (unsigned char*)(ws + off); off = align256(off + (size_t)E);
    int* hist_d     = (int*)(ws + off);    off = align256(off + (size_t)M * sizeof(int));
    int* hist_s     = (int*)(ws + off);    off = align256(off + (size_t)M * sizeof(int));
    int* Td         = (int*)(ws + off);    off = align256(off + (size_t)nbk * sizeof(int));
    int* Ts         = (int*)(ws + off);    off = align256(off + (size_t)nbk * sizeof(int));
    int* cnt_out    = (int*)(ws + off);    off = align256(off + (size_t)N * sizeof(int));
    int* cnt_in     = (int*)(ws + off);    off = align256(off + (size_t)N * sizeof(int));
    int* row_ptr    = (int*)(ws + off);    off = align256(off + (size_t)(N + 1) * sizeof(int));

    const int pslice = (E + PA_BLOCKS - 1) / PA_BLOCKS;

    // Dual radix-partition CSR build + degree counts (zero device atomics)
    part_hist_kernel<<<PA_BLOCKS, 256, 0, stream>>>(src, dst, hist_d, hist_s, nbk, E, pslice);
    row_scan_kernel<<<2 * nbk, 512, 0, stream>>>(hist_d, hist_s, Td, Ts, nbk);
    tot_scan_kernel<<<1, 1024, 0, stream>>>(Td, Ts, nbk);
    part_scatter_kernel<<<PA_BLOCKS, 256, 0, stream>>>(src, dst, hist_d, hist_s, Td, Ts,
                                                       ebuf, sbuf, nbk, E, pslice);
    bucket_csr_kernel<<<nbk, 256, 0, stream>>>(ebuf, sbuf, Td, Ts, csr_src,
                                               cnt_in, cnt_out, row_ptr, nbk, N, E);

    const int gemm_blocks = (N + 63) / 64;
    const int agg_blocks  = (N + 3) / 4;

    // Layer 1: Y = fp16[(X @ W1) * rs_out] ; agg -> d_out (hidden, relu)
    gemm_scale_kernel<128><<<gemm_blocks, 256, 0, stream>>>(x, W1, cnt_out, Y, N);
    aggregate_kernel<true><<<agg_blocks, 256, 0, stream>>>(Y, row_ptr, csr_src, cnt_in, b1, out, N);

    // Layer 2: Y = fp16[(H @ W2) * rs_out] ; agg -> d_out (final)
    gemm_scale_kernel<64><<<gemm_blocks, 256, 0, stream>>>(out, W2, cnt_out, Y, N);
    aggregate_kernel<false><<<agg_blocks, 256, 0, stream>>>(Y, row_ptr, csr_src, cnt_in, b2, out, N);
}